// Round 9
// baseline (144.000 us; speedup 1.0000x reference)
//
#include <hip/hip_runtime.h>
#include <cstddef>

#define CC 256
#define HH 128
#define WW 128
#define HW (HH*WW)          // 16384

typedef __attribute__((ext_vector_type(8))) short short8v;   // 8 bf16
typedef __attribute__((ext_vector_type(4))) float float4v;   // MFMA acc

__device__ __forceinline__ short f2bf(float x) {
    unsigned u = __float_as_uint(x);
    u += 0x7FFFu + ((u >> 16) & 1u);      // RNE to bf16
    return (short)(u >> 16);
}
__device__ __forceinline__ float4 add4(float4 a, float4 b) {
    float4 r; r.x=a.x+b.x; r.y=a.y+b.y; r.z=a.z+b.z; r.w=a.w+b.w; return r;
}
__device__ __forceinline__ float4 scale4(float4 a, float s) {
    float4 r; r.x=a.x*s; r.y=a.y*s; r.z=a.z*s; r.w=a.w*s; return r;
}
__device__ __forceinline__ float4 shflx4(float4 v, int m) {
    float4 r;
    r.x = __shfl_xor(v.x, m); r.y = __shfl_xor(v.y, m);
    r.z = __shfl_xor(v.z, m); r.w = __shfl_xor(v.w, m);
    return r;
}
__device__ __forceinline__ float hsum4(float4 v) { return v.x+v.y+v.z+v.w; }

// pinned-issue 16B global load (compiler cannot sink/reorder vs memory asm)
#define GLD4(dst, addr, OFFSTR) \
    asm volatile("global_load_dwordx4 %0, %1, off offset:" OFFSTR \
                 : "=v"(dst) : "v"(addr) : "memory")

#define WAITVM(NSTR) { asm volatile("s_waitcnt vmcnt(" NSTR ")" ::: "memory"); \
                       __builtin_amdgcn_sched_barrier(0); }
// barrier that waits only LDS (keeps global loads/stores in flight)
#define BAR_LDS { asm volatile("s_waitcnt lgkmcnt(0)" ::: "memory"); \
                  __builtin_amdgcn_sched_barrier(0); \
                  __builtin_amdgcn_s_barrier(); }

#define ISSUE_A(P) { GLD4(aR[0], P, "0");    GLD4(aR[1], P, "512");  \
                     GLD4(aR[2], P, "1024"); GLD4(aR[3], P, "1536"); \
                     GLD4(aR[4], P, "2048"); GLD4(aR[5], P, "2560"); \
                     GLD4(aR[6], P, "3072"); GLD4(aR[7], P, "3584"); }
#define ISSUE_C(P) { GLD4(cR[0], P, "0");    GLD4(cR[1], P, "512");  \
                     GLD4(cR[2], P, "1024"); GLD4(cR[3], P, "1536"); }
#define ISSUE_D(P) { GLD4(dR[0], P, "0");    GLD4(dR[1], P, "512");  \
                     GLD4(dR[2], P, "1024"); GLD4(dR[3], P, "1536"); }

// ---- phase A: build keys (kH, kWT) in LDS from t1 registers ----
__device__ __forceinline__ void phaseA(
    const float4* aR, short* kH, short* kWT, int l, int q, int g)
{
    float4 s = add4(add4(add4(aR[0],aR[1]), add4(aR[2],aR[3])),
                    add4(add4(aR[4],aR[5]), add4(aR[6],aR[7])));
    float4 m4 = scale4(s, 0.125f);
    short4 p; p.x=f2bf(m4.x); p.y=f2bf(m4.y); p.z=f2bf(m4.z); p.w=f2bf(m4.w);
    *(short4*)&kH[g*128 + ((q*4) ^ ((g&7)<<3))] = p;
    const int kw = q >> 1;
    const int sw = (kw & 7) << 3;
    #pragma unroll
    for (int r = 0; r < 8; ++r) {
        float rs = hsum4(aR[r]);
        rs += __shfl_xor(rs, 1);
        if ((l & 1) == 0)
            kWT[kw*128 + ((g*8+r) ^ sw)] = f2bf(rs * 0.125f);
    }
}

// ---- process one t2 half: val global stores (8 instrs) + LDS tile staging ----
__device__ __forceinline__ void process_half(
    float4 x0, float4 x1, float4 x2, float4 x3, int half, int bc,
    unsigned short* valHT, unsigned short* valWbf,
    short* t2lds, short* t2T, int l, int q, int g, int wv)
{
    // pool H -> valHT bf16 [w][16]  (4 store instrs, lanes l<32)
    {
        float4 sB = add4(add4(x0,x1), add4(x2,x3));
        float4 f8 = add4(sB, shflx4(sB, 32));
        const int k = half*8 + wv;
        const size_t vb = (size_t)bc * 2048;
        if (l < 32) {
            valHT[vb + (q*4+0)*16 + k] = (unsigned short)f2bf(f8.x * 0.125f);
            valHT[vb + (q*4+1)*16 + k] = (unsigned short)f2bf(f8.y * 0.125f);
            valHT[vb + (q*4+2)*16 + k] = (unsigned short)f2bf(f8.z * 0.125f);
            valHT[vb + (q*4+3)*16 + k] = (unsigned short)f2bf(f8.w * 0.125f);
        }
    }
    // pool W -> valWbf bf16 [h][16]  (4 store instrs, even lanes)
    {
        const int kw = q >> 1;
        float r0 = hsum4(x0), r1 = hsum4(x1), r2 = hsum4(x2), r3 = hsum4(x3);
        r0 += __shfl_xor(r0, 1); r1 += __shfl_xor(r1, 1);
        r2 += __shfl_xor(r2, 1); r3 += __shfl_xor(r3, 1);
        if ((l & 1) == 0) {
            const size_t vb = (size_t)bc*2048 + (size_t)(half*64 + g*4)*16 + kw;
            valWbf[vb +  0] = (unsigned short)f2bf(r0 * 0.125f);
            valWbf[vb + 16] = (unsigned short)f2bf(r1 * 0.125f);
            valWbf[vb + 32] = (unsigned short)f2bf(r2 * 0.125f);
            valWbf[vb + 48] = (unsigned short)f2bf(r3 * 0.125f);
        }
    }
    // stage LDS: row-major + transposed (bf16)
    short4 s0, s1, s2, s3;
    s0.x=f2bf(x0.x); s0.y=f2bf(x0.y); s0.z=f2bf(x0.z); s0.w=f2bf(x0.w);
    s1.x=f2bf(x1.x); s1.y=f2bf(x1.y); s1.z=f2bf(x1.z); s1.w=f2bf(x1.w);
    s2.x=f2bf(x2.x); s2.y=f2bf(x2.y); s2.z=f2bf(x2.z); s2.w=f2bf(x2.w);
    s3.x=f2bf(x3.x); s3.y=f2bf(x3.y); s3.z=f2bf(x3.z); s3.w=f2bf(x3.w);
    const int hl0 = g*4;
    *(short4*)&t2lds[(hl0+0)*128 + ((q*4) ^ (((hl0+0)&7)<<3))] = s0;
    *(short4*)&t2lds[(hl0+1)*128 + ((q*4) ^ (((hl0+1)&7)<<3))] = s1;
    *(short4*)&t2lds[(hl0+2)*128 + ((q*4) ^ (((hl0+2)&7)<<3))] = s2;
    *(short4*)&t2lds[(hl0+3)*128 + ((q*4) ^ (((hl0+3)&7)<<3))] = s3;
    const int swt = (q & 7) << 3;
    const int hb  = hl0 ^ swt;
    short4 p;
    p.x=s0.x; p.y=s1.x; p.z=s2.x; p.w=s3.x;
    *(short4*)&t2T[(q*4+0)*64 + hb] = p;
    p.x=s0.y; p.y=s1.y; p.z=s2.y; p.w=s3.y;
    *(short4*)&t2T[(q*4+1)*64 + hb] = p;
    p.x=s0.z; p.y=s1.z; p.z=s2.z; p.w=s3.z;
    *(short4*)&t2T[(q*4+2)*64 + hb] = p;
    p.x=s0.w; p.y=s1.w; p.z=s2.w; p.w=s3.w;
    *(short4*)&t2T[(q*4+3)*64 + hb] = p;
}

__device__ __forceinline__ void mfma_half(
    const short* t2lds, const short* t2T, const short* kH, const short* kWT,
    int wv, int l, int half, float4v& accH, float4v& accW)
{
    if ((wv >> 2) == half) {
        const int hl = (wv & 3)*16 + (l & 15);
        const int kb = l & 15;
        #pragma unroll
        for (int ws2 = 0; ws2 < 4; ++ws2) {
            const int wb = ws2*32 + (l>>4)*8;
            short8v A = *(const short8v*)&t2lds[hl*128 + (wb ^ ((hl&7)<<3))];
            short8v B = *(const short8v*)&kH  [kb*128 + (wb ^ ((kb&7)<<3))];
            accH = __builtin_amdgcn_mfma_f32_16x16x32_bf16(A, B, accH, 0, 0, 0);
        }
    }
    {
        const int kb = l & 15;
        const int w  = wv*16 + (l & 15);
        const int swt = ((w >> 2) & 7) << 3;
        #pragma unroll
        for (int hs = 0; hs < 2; ++hs) {
            const int hloc = hs*32 + (l>>4)*8;
            const int hg   = half*64 + hloc;
            short8v A = *(const short8v*)&kWT[kb*128 + (hg ^ ((kb&7)<<3))];
            short8v B = *(const short8v*)&t2T[w*64   + (hloc ^ swt)];
            accW = __builtin_amdgcn_mfma_f32_16x16x32_bf16(A, B, accW, 0, 0, 0);
        }
    }
}

// ============ Kernel 1: fused pooling + both energies, 4-c pipeline ============
// grid 512: b = bid&7, grp = bid>>3 (4 c's each). block 512 (8 waves).
// Cross-c software pipeline: c+1's loads in flight during c's compute.
__global__ __launch_bounds__(512, 4) void fused_pool_energy(
    const float* __restrict__ t1, const float* __restrict__ t2,
    unsigned short* __restrict__ valHT, unsigned short* __restrict__ valWbf,
    float* __restrict__ PH, float* __restrict__ PW)
{
    __shared__ __align__(16) short t2lds[64*128];   // 16KB
    __shared__ __align__(16) short t2T  [128*64];   // 16KB
    __shared__ __align__(16) short kH   [16*128];   //  4KB
    __shared__ __align__(16) short kWT  [16*128];   //  4KB

    const int bid = blockIdx.x;
    const int b   = bid & 7;
    const int grp = bid >> 3;          // 0..63
    const int c0  = grp * 4;
    const int tid = threadIdx.x;
    const int l   = tid & 63;
    const int wv  = tid >> 6;
    const int q   = tid & 31;
    const int g   = tid >> 5;

    const float4* ap0 = (const float4*)(t1 + ((size_t)b*CC + c0)*HW) + g*256 + q;
    const float4* cp0 = (const float4*)(t2 + ((size_t)b*CC + c0)*HW) + g*128 + q;
    // c stride in float4 units = HW/4 = 4096

    float4 aR[8], cR[4], dR[4];
    float4v accH = {0.f,0.f,0.f,0.f};
    float4v accW = {0.f,0.f,0.f,0.f};

    // ---- prologue: A0,C0,D0; keys(0); A1 ----
    ISSUE_A(ap0); ISSUE_C(cp0); ISSUE_D(cp0 + 2048);
    WAITVM("8");                 // A0 landed (C0,D0 = 8 outstanding)
    phaseA(aR, kH, kWT, l, q, g);
    BAR_LDS;
    ISSUE_A(ap0 + 4096);         // A1

    #pragma unroll
    for (int ci = 0; ci < 4; ++ci) {
        const int bc = b*CC + c0 + ci;
        const float4* cpi = cp0 + ci*4096;

        // C(ci): after-count = D(ci)4 + A(ci+1)8 (last: 4)
        if (ci < 3) WAITVM("12") else WAITVM("4");
        process_half(cR[0],cR[1],cR[2],cR[3], 0, bc, valHT, valWbf,
                     t2lds, t2T, l, q, g, wv);
        BAR_LDS;
        mfma_half(t2lds, t2T, kH, kWT, wv, l, 0, accH, accW);
        BAR_LDS;

        // D(ci): after-count = A(ci+1)8 + h0-stores(ci)8 (last: 8)
        if (ci < 3) WAITVM("16") else WAITVM("8");
        process_half(dR[0],dR[1],dR[2],dR[3], 1, bc, valHT, valWbf,
                     t2lds, t2T, l, q, g, wv);
        BAR_LDS;
        if (ci < 3) { ISSUE_C(cpi + 4096); ISSUE_D(cpi + 4096 + 2048); }
        mfma_half(t2lds, t2T, kH, kWT, wv, l, 1, accH, accW);
        BAR_LDS;

        if (ci < 3) {
            // A(ci+1): after-count = h0st(ci)8 + h1st(ci)8 + C/D(ci+1)8 = 24
            WAITVM("24");
            phaseA(aR, kH, kWT, l, q, g);
            BAR_LDS;
            if (ci < 2) ISSUE_A(ap0 + (ci+2)*4096);
        }
    }

    // ---------- write partials (accumulated over 4 c's) ----------
    {
        const size_t pb = (size_t)bid * 2048;
        #pragma unroll
        for (int r = 0; r < 4; ++r) {
            const int h = (wv>>2)*64 + (wv&3)*16 + (l>>4)*4 + r;
            PH[pb + (size_t)h*16 + (l&15)] = accH[r];
            const int k = (l>>4)*4 + r;
            PW[pb + (size_t)k*128 + wv*16 + (l&15)] = accW[r];
        }
    }
}

// ============ Kernel 2: reduce 64 grp-records -> energy[8][4096] ============
__global__ __launch_bounds__(256) void energy_reduce(
    const float* __restrict__ PH, const float* __restrict__ PW,
    float* __restrict__ energy, float* __restrict__ bmin, float* __restrict__ bmax)
{
    const int bidx = blockIdx.x;           // 0..511
    const int tid  = threadIdx.x;
    const int ol   = tid & 63, qd = tid >> 6;
    const int o    = bidx*64 + ol;         // 0..32767
    __shared__ float red[4][64];

    const int isW = o >> 14;
    const int oo  = o & 16383;
    const int b   = oo >> 11, i = oo & 2047;
    const float* P = (isW ? PW : PH) + (size_t)b*2048 + i;
    float s = 0.f;
    #pragma unroll
    for (int j = 0; j < 16; ++j)
        s += P[(size_t)((qd*16 + j)*8) * 2048];     // grp stride = 8 records
    red[qd][ol] = s;
    __syncthreads();

    if (tid < 64) {
        float v = red[0][tid] + red[1][tid] + red[2][tid] + red[3][tid];
        const int o2 = bidx*64 + tid;
        const int oo2 = o2 & 16383;
        const int b2 = oo2 >> 11, i2 = oo2 & 2047;
        const size_t dst = (o2 >> 14)
            ? ((size_t)b2*4096 + 2048 + (size_t)(i2 & 127)*16 + (i2 >> 7))
            : ((size_t)b2*4096 + i2);
        energy[dst] = v;
        float mn = v, mx = v;
        #pragma unroll
        for (int sft = 32; sft > 0; sft >>= 1) {
            mn = fminf(mn, __shfl_xor(mn, sft));
            mx = fmaxf(mx, __shfl_xor(mx, sft));
        }
        if (tid == 0) { bmin[bidx] = mn; bmax[bidx] = mx; }
    }
}

// ============ Kernel 3: softmax (8 blocks) -> bf16 att [h][16] and [w][16] ====
__global__ __launch_bounds__(1024) void softmax_kernel(
    const float* __restrict__ energy, const float* __restrict__ bmin,
    const float* __restrict__ bmax,
    unsigned short* __restrict__ aHbf, unsigned short* __restrict__ aWbf)
{
    const int b = blockIdx.x, tid = threadIdx.x;
    const int lane = tid & 63, wid = tid >> 6;     // 16 waves
    __shared__ float smn[16], smx[16], sred[16], bc2[2];

    float mn = 3.0e38f, mx = -3.0e38f;
    if (tid < 512) { mn = bmin[tid]; mx = bmax[tid]; }
    #pragma unroll
    for (int s = 32; s > 0; s >>= 1) {
        mn = fminf(mn, __shfl_xor(mn, s));
        mx = fmaxf(mx, __shfl_xor(mx, s));
    }
    if (lane == 0) { smn[wid] = mn; smx[wid] = mx; }
    __syncthreads();
    if (tid == 0) {
        float a = smn[0], m = smx[0];
        #pragma unroll
        for (int i = 1; i < 16; ++i) { a = fminf(a, smn[i]); m = fmaxf(m, smx[i]); }
        bc2[0] = a; bc2[1] = m;
    }
    __syncthreads();
    const float gmn = bc2[0];
    const float inv = 1.0f / (bc2[1] - gmn);

    float4 v = ((const float4*)energy)[b*1024 + tid];
    float4 e;
    e.x = __expf((v.x - gmn) * inv);
    e.y = __expf((v.y - gmn) * inv);
    e.z = __expf((v.z - gmn) * inv);
    e.w = __expf((v.w - gmn) * inv);
    float loc = e.x + e.y + e.z + e.w;
    #pragma unroll
    for (int s = 32; s > 0; s >>= 1) loc += __shfl_down(loc, s);
    if (lane == 0) sred[wid] = loc;
    __syncthreads();
    if (tid == 0) {
        float a = 0.f;
        #pragma unroll
        for (int j = 0; j < 16; ++j) a += sred[j];
        bc2[0] = 1.0f / a;
    }
    __syncthreads();
    const float r = bc2[0];
    short4 p;
    p.x = f2bf(e.x * r); p.y = f2bf(e.y * r);
    p.z = f2bf(e.z * r); p.w = f2bf(e.w * r);
    if (tid < 512)
        *(short4*)&aHbf[(size_t)b*2048 + tid*4] = p;
    else
        *(short4*)&aWbf[(size_t)b*2048 + (tid-512)*4] = p;
}

// ============ Kernel 4: recombination via rank-32 MFMA ============
// grid 2048 (b = bid&7, c = bid>>3), block 256 (4 waves).
__global__ __launch_bounds__(256) void out_kernel(
    const float* __restrict__ t2,
    const unsigned short* __restrict__ valHT,   // [b][c][w][16]
    const unsigned short* __restrict__ valWbf,  // [b][c][h][16]
    const unsigned short* __restrict__ aHbf,    // [b][h][16]
    const unsigned short* __restrict__ aWbf,    // [b][w][16]
    float* __restrict__ out)
{
    const int bid = blockIdx.x;
    const int b = bid & 7, c = bid >> 3;
    const int bc = b*CC + c;
    const int tid = threadIdx.x;
    const int l  = tid & 63;
    const int wv = tid >> 6;       // 0..3
    const int ln = l & 15;
    const int q4 = l >> 4;         // k-quadrant
    const size_t tb = (size_t)bc * HW;

    const unsigned short* vHT = valHT  + (size_t)bc*2048;   // [w][16]
    const unsigned short* vW  = valWbf + (size_t)bc*2048;   // [h][16]
    const unsigned short* aH  = aHbf + (size_t)b*2048;      // [h][16]
    const unsigned short* aW  = aWbf + (size_t)b*2048;      // [w][16]

    short8v Bf[8];
    {
        const unsigned short* src = (q4 < 2) ? vHT : aW;
        #pragma unroll
        for (int tw = 0; tw < 8; ++tw)
            Bf[tw] = *(const short8v*)&src[(tw*16 + ln)*16 + (q4 & 1)*8];
    }

    #pragma unroll
    for (int t = 0; t < 2; ++t) {
        const int th = wv*2 + t;
        const unsigned short* asrc = (q4 < 2) ? aH : vW;
        short8v Af = *(const short8v*)&asrc[(th*16 + ln)*16 + (q4 & 1)*8];
        #pragma unroll
        for (int tw = 0; tw < 8; ++tw) {
            float4v acc = {0.f,0.f,0.f,0.f};
            acc = __builtin_amdgcn_mfma_f32_16x16x32_bf16(Af, Bf[tw], acc, 0, 0, 0);
            const size_t base = tb + (size_t)(th*16 + q4*4)*128 + tw*16 + ln;
            #pragma unroll
            for (int r = 0; r < 4; ++r) {
                const float tv = t2[base + (size_t)r*128];
                out[base + (size_t)r*128] = fmaf(0.5f, acc[r], tv);
            }
        }
    }
}

extern "C" void kernel_launch(void* const* d_in, const int* in_sizes, int n_in,
                              void* d_out, int out_size, void* d_ws, size_t ws_size,
                              hipStream_t stream)
{
    const float* t1 = (const float*)d_in[0];
    const float* t2 = (const float*)d_in[1];
    float* out = (float*)d_out;
    char*  ws  = (char*)d_ws;

    unsigned short* valHT  = (unsigned short*)ws;                       // 8 MB
    unsigned short* valWbf = (unsigned short*)(ws + ((size_t)8 << 20)); // 8 MB
    float* energy = (float*)(ws + ((size_t)16 << 20));                  // 128 KB
    float* bmin   = energy + 32768;
    float* bmax   = bmin + 512;
    unsigned short* aHbf = (unsigned short*)(ws + ((size_t)17 << 20));  // 32 KB
    unsigned short* aWbf = aHbf + 8*2048;                               // 32 KB

    // partials live in d_out (8.4 MB of 134 MB), overwritten by out_kernel
    float* PH = out;                        // 512*2048 floats = 4 MB
    float* PW = out + (size_t)1048576;      // 4 MB

    hipLaunchKernelGGL(fused_pool_energy, dim3(512), dim3(512), 0, stream,
                       t1, t2, valHT, valWbf, PH, PW);
    hipLaunchKernelGGL(energy_reduce, dim3(512), dim3(256), 0, stream,
                       PH, PW, energy, bmin, bmax);
    hipLaunchKernelGGL(softmax_kernel, dim3(8), dim3(1024), 0, stream,
                       energy, bmin, bmax, aHbf, aWbf);
    hipLaunchKernelGGL(out_kernel, dim3(2048), dim3(256), 0, stream,
                       t2, valHT, valWbf, aHbf, aWbf, out);
}